// Round 13
// baseline (479.630 us; speedup 1.0000x reference)
//
#include <hip/hip_runtime.h>
#include <cstdint>
#include <cstddef>

typedef unsigned short u16;
typedef __attribute__((ext_vector_type(2))) unsigned short u16x2;
typedef __attribute__((ext_vector_type(4))) unsigned short u16x4;
typedef __attribute__((ext_vector_type(8))) unsigned short u16x8;
typedef __attribute__((ext_vector_type(4))) float f32x4;
typedef __attribute__((ext_vector_type(8))) __bf16 bf16x8;

#define B_    2
#define L_    2048
#define DIM_  2048
#define H_    16
#define HD_   128
#define NQKV_ 6144
#define M_    4096   // B_*L_

__device__ __forceinline__ float b2f(u16 h) {
  union { unsigned u; float f; } v; v.u = ((unsigned)h) << 16; return v.f;
}
__device__ __forceinline__ u16 f2bf(float f) {
  unsigned u = __float_as_uint(f);
  u += 0x7fffu + ((u >> 16) & 1u);   // RNE
  return (u16)(u >> 16);
}
__device__ __forceinline__ f32x4 mfma16(bf16x8 a, bf16x8 b, f32x4 c) {
  return __builtin_amdgcn_mfma_f32_16x16x32_bf16(a, b, c, 0, 0, 0);
}
__device__ __forceinline__ void async16(const void* g, void* l) {
  __builtin_amdgcn_global_load_lds(
      (const __attribute__((address_space(1))) unsigned*)g,
      (__attribute__((address_space(3))) unsigned*)l, 16, 0, 0);
}

// ---------------------------------------------------------------------------
// Pre-pass 1: straight f32 -> bf16 convert (x). 4 elems/thread.
// ---------------------------------------------------------------------------
__global__ __launch_bounds__(256) void cvt_bf16(
    const float* __restrict__ src, u16* __restrict__ dst) {
  int i = (blockIdx.x * 256 + threadIdx.x) * 4;
  f32x4 v = *(const f32x4*)&src[i];
  u16x4 o;
  #pragma unroll
  for (int j = 0; j < 4; ++j) o[j] = f2bf(v[j]);
  *(u16x4*)&dst[i] = o;
}

// ---------------------------------------------------------------------------
// Pre-pass 2: f32 (R x C) -> bf16 transposed (C x R). 64x64 LDS tile.
// ---------------------------------------------------------------------------
__global__ __launch_bounds__(256) void transpose_cvt(
    const float* __restrict__ src, u16* __restrict__ dst, int R, int C) {
  __shared__ u16 tile[64][66];
  int r0 = blockIdx.y * 64, c0 = blockIdx.x * 64;
  #pragma unroll
  for (int i = 0; i < 16; ++i) {
    int f = i * 256 + threadIdx.x;
    int r = f >> 6, c = f & 63;
    tile[r][c] = f2bf(src[(size_t)(r0 + r) * C + (c0 + c)]);
  }
  __syncthreads();
  #pragma unroll
  for (int i = 0; i < 8; ++i) {
    int f = i * 256 + threadIdx.x;
    int cr = f >> 5, rp = (f & 31) * 2;
    u16x2 v = {tile[rp][cr], tile[rp + 1][cr]};
    *(u16x2*)&dst[(size_t)(c0 + cr) * R + (r0 + rp)] = v;
  }
}

// ---------------------------------------------------------------------------
// m97-style GEMM, BK=64 (round-12, proven −27 us): C[M,N] = A*Bt^T, bf16,
// async16 staging, 128x128 tile, 256 thr. BK=64 halves barrier count;
// LDS 32 KB. Tiles XOR-swizzled (elem = row*64 + (col ^ ((row&7)<<3)))
// via inverse-swizzled global source (rule #21); post-swizzle bank group
// (kk*4+qd)^(ln&7) = 8 lanes/group = b128 minimum.
// MODE 1: scatter epilogue into Q/K/V; t/h/b hoisted; Q/K interleaved-pair.
// MODE 2: bias-add epilogue, f32 row-major store.
// ---------------------------------------------------------------------------
template <int MODE>
__global__ __launch_bounds__(256) void gemm_bt(
    const u16* __restrict__ A, const u16* __restrict__ Bt,
    u16* __restrict__ D0, u16* __restrict__ D1, u16* __restrict__ D2,
    const float* __restrict__ bias, float* __restrict__ outp,
    int M, int N, int K) {
  __shared__ __align__(16) u16 Alds[128 * 64];
  __shared__ __align__(16) u16 Blds[128 * 64];
  const int tid = threadIdx.x;
  const int wave = tid >> 6;
  const int wm = wave >> 1, wn = wave & 1;
  const int ln = tid & 15, qd = (tid >> 4) & 3;
  const int m0 = blockIdx.y * 128, n0 = blockIdx.x * 128;

  f32x4 acc[4][4];
  #pragma unroll
  for (int i = 0; i < 4; ++i)
    #pragma unroll
    for (int j = 0; j < 4; ++j) acc[i][j] = (f32x4){0.f, 0.f, 0.f, 0.f};

  for (int k0 = 0; k0 < K; k0 += 64) {
    __syncthreads();                     // prev iter's fragment ds_reads done
    #pragma unroll
    for (int j = 0; j < 4; ++j) {
      int oe = j * 2048 + tid * 8;       // linear LDS elem offset (128x64)
      int se = oe ^ (((oe >> 6) & 7) << 3);  // swizzled source elem
      int r = oe >> 6, c = se & 63;
      async16(&A[(size_t)(m0 + r) * K + (k0 + c)], &Alds[j * 2048 + wave * 512]);
      async16(&Bt[(size_t)(n0 + r) * K + (k0 + c)], &Blds[j * 2048 + wave * 512]);
    }
    __syncthreads();                     // drains vmcnt before use
    #pragma unroll
    for (int kk = 0; kk < 2; ++kk) {     // two 32-wide K-slices
      bf16x8 af[4], bfr[4];
      #pragma unroll
      for (int mi = 0; mi < 4; ++mi) {
        int arow = wm * 64 + mi * 16 + ln;
        af[mi] = *(const bf16x8*)&Alds[arow * 64 +
                     ((kk * 32 + qd * 8) ^ ((arow & 7) << 3))];
      }
      #pragma unroll
      for (int ni = 0; ni < 4; ++ni) {
        int brow = wn * 64 + ni * 16 + ln;
        bfr[ni] = *(const bf16x8*)&Blds[brow * 64 +
                     ((kk * 32 + qd * 8) ^ ((brow & 7) << 3))];
      }
      #pragma unroll
      for (int mi = 0; mi < 4; ++mi)
        #pragma unroll
        for (int ni = 0; ni < 4; ++ni)
          acc[mi][ni] = mfma16(af[mi], bfr[ni], acc[mi][ni]);
    }
  }

  // epilogue: C/D layout col=lane&15, row=quad*4+reg  [m89-verified]
  if (MODE == 2) {
    #pragma unroll
    for (int mi = 0; mi < 4; ++mi)
      #pragma unroll
      for (int ni = 0; ni < 4; ++ni)
        #pragma unroll
        for (int r = 0; r < 4; ++r) {
          int row = m0 + wm * 64 + mi * 16 + qd * 4 + r;
          int col = n0 + wn * 64 + ni * 16 + ln;
          outp[(size_t)row * N + col] = acc[mi][ni][r] + bias[col];
        }
  } else {
    const int t  = n0 >> 11;             // 0=q, 1=k, 2=v   (block-uniform)
    const int hh = (n0 & 2047) >> 7;     // head            (block-uniform)
    const int bb = m0 >> 11;             // batch           (block-uniform)
    const int l0 = (m0 & 2047) + wm * 64;
    // Q/K (t<2): interleaved-pair pos = ((ln+ni*16)<<1)|wn; V natural.
    const int d0    = (t != 2) ? (((ln) << 1) | wn) : (wn * 64 + ln);
    const int dstep = (t != 2) ? 32 : 16;
    u16* dst = (t == 0) ? D0 : ((t == 1) ? D1 : D2);
    u16* basep = dst + ((size_t)(bb * H_ + hh) * L_) * HD_;
    #pragma unroll
    for (int mi = 0; mi < 4; ++mi)
      #pragma unroll
      for (int r = 0; r < 4; ++r) {
        int l = l0 + mi * 16 + qd * 4 + r;
        #pragma unroll
        for (int ni = 0; ni < 4; ++ni)
          basep[(size_t)l * HD_ + d0 + ni * dstep] = f2bf(acc[mi][ni][r]);
      }
  }
}

// ---------------------------------------------------------------------------
// In-place rotary on Q and K in INTERLEAVED-PAIR layout (B*H, L, 128):
// position 2d = x1(d), 2d+1 = x2(d). Fully vectorized: each thread does
// 4 pairs = one u16x8 (16 B) load + f32x4 cos + f32x4 sin + one 16 B store.
// ---------------------------------------------------------------------------
__global__ __launch_bounds__(256) void rotary_k(
    u16* __restrict__ Q, u16* __restrict__ Kb,
    const float* __restrict__ cs, const float* __restrict__ sn) {
  const int tid = threadIdx.x;
  const int tensor = tid >> 7;            // 0 = Q, 1 = K
  const int rsub = (tid >> 4) & 7;        // row within block's 8
  const int j = tid & 15;                 // 16 threads per row
  const int row = blockIdx.x * 8 + rsub;  // flat (bh*L + l)
  const int l = row & (L_ - 1);
  u16* P = tensor ? Kb : Q;
  size_t base = (size_t)row * HD_ + j * 8;
  u16x8 v = *(const u16x8*)&P[base];
  f32x4 c = *(const f32x4*)&cs[l * 64 + j * 4];
  f32x4 s = *(const f32x4*)&sn[l * 64 + j * 4];
  u16x8 o;
  #pragma unroll
  for (int e = 0; e < 4; ++e) {
    float x1 = b2f(v[2 * e]), x2 = b2f(v[2 * e + 1]);
    o[2 * e]     = f2bf(x1 * c[e] - x2 * s[e]);
    o[2 * e + 1] = f2bf(x2 * c[e] + x1 * s[e]);
  }
  *(u16x8*)&P[base] = o;
}

// ---------------------------------------------------------------------------
// Flash attention. grid (16 qtiles, 32 bh), 256 thr (4 waves).
// Q,K,V all (B*H, L, 128) bf16. BM=128, BN=64 keys/iter.
//
// ROUND-12 STRUCTURE + EARLY K-PREFETCH (plain __syncthreads ONLY):
// K[it+1] async16 issues AFTER B3 of iter it instead of after B1 of it+1.
// Dataflow proof: at B2(it) the outstanding vmem is K[it] (issued B3(it-1),
// covered by PV + V-loads + B1 + V-stores, 400+ cyc) + vv(it) (consumed
// before B2) -> B2's implicit vmcnt(0) drain is nearly free (was the one
// remaining 150-350 cyc/iter exposed stall). K[it+1] lands in Klds only
// during PV / next V-loads (disjoint LDS regions); B3 guarantees all waves'
// QK^T ds_reads are done before the issue. Round 8 tried this dataflow
// WITH inline-asm fences and died on VGPR (140); this isolates the
// placement with zero fences. If VGPR > 128 -> revert (occupancy cliff).
//
// Session rules (rounds 4-8):
//  - VGPR <= 128 or occupancy halves (64-granular quantum).
//  - NO sched_barrier/inline-asm fences here (pin live ranges, +24 VGPR).
//  - NO defer-max branch (+24 VGPR).
//  - Occupancy (3 blocks/CU) is the latency hider.
//  - attn is NOT memory-bound (round 11: FETCH 139->25 MB cost 11 us).
//
// LDS swizzles (both-sides, rule #21):
//   K/Q tiles: elem = row*128 + (col ^ ((row&7)<<3)); staged via inverse-
//     swizzled GLOBAL source (global_load_lds writes LDS linearly).
//   Vlds [128][64]: elem = row*64 + (col ^ (((row>>1)&7)<<3)).
//   Plds stride-72. LDS = 50 KB -> 3 blocks/CU.
// Deferred l-reduce: lsum kept PER-LANE, quad-reduced once in epilogue.
// ---------------------------------------------------------------------------
__global__ __launch_bounds__(256, 4) void attn_k(
    const u16* __restrict__ Q, const u16* __restrict__ Kb,
    const u16* __restrict__ V, u16* __restrict__ Ao) {
  __shared__ __align__(16) u16 lds[25600];     // 50 KB
  u16* Klds = lds;               // [64 keys][128 d]  (swizzled)
  u16* Vlds = lds + 8192;        // [128 d][64 keys]  (swizzled)
  u16* Plds = lds + 16384;       // [128 q][72], keys 0..63 used
  const int tid = threadIdx.x;
  const int w = tid >> 6, lane = tid & 63;
  const int ln = lane & 15, qd = lane >> 4;
  const int qt = blockIdx.x, bh = blockIdx.y;
  const int b = bh >> 4, h = bh & 15;
  const size_t slab = (size_t)bh * (L_ * HD_);
  const int vd0 = 2 * lane;                    // V staging: d-pair

  // stage Q tile (contiguous 32 KB, overlays K+V) via async16, pre-swizzled
  #pragma unroll
  for (int j = 0; j < 8; ++j) {
    int oe = j * 2048 + w * 512 + lane * 8;        // linear LDS elem offset
    int se = oe ^ (((oe >> 7) & 7) << 3);          // swizzled global source
    async16(&Q[slab + (size_t)qt * 16384 + se], &lds[j * 2048 + w * 512]);
  }
  __syncthreads();
  bf16x8 aq[2][4];                         // Q fragments in registers
  #pragma unroll
  for (int mi = 0; mi < 2; ++mi) {
    int qrow = w * 32 + mi * 16 + ln;
    #pragma unroll
    for (int kc = 0; kc < 4; ++kc)
      aq[mi][kc] = *(const bf16x8*)&lds[qrow * 128 +
                                        ((kc * 32 + qd * 8) ^ ((qrow & 7) << 3))];
  }
  __syncthreads();                         // all aq reads done before K[0] lands

  f32x4 o[2][8];
  #pragma unroll
  for (int i = 0; i < 2; ++i)
    #pragma unroll
    for (int j = 0; j < 8; ++j) o[i][j] = (f32x4){0.f, 0.f, 0.f, 0.f};
  float mst[2][4], lsum[2][4];             // lsum = PER-LANE partial sum
  #pragma unroll
  for (int i = 0; i < 2; ++i)
    #pragma unroll
    for (int r = 0; r < 4; ++r) { mst[i][r] = -1e30f; lsum[i][r] = 0.f; }
  const float SC = 0.12751744f;            // (1/sqrt(128)) * log2(e)

  // prologue: K[0] in flight (drained by B2 of iter 0)
  #pragma unroll
  for (int j = 0; j < 4; ++j) {
    int oe = j * 2048 + w * 512 + lane * 8;
    int se = oe ^ (((oe >> 7) & 7) << 3);
    async16(&Kb[slab + se], &Klds[j * 2048 + w * 512]);
  }

  for (int it = 0; it < 32; ++it) {
    // V global loads -> regs (no LDS touch; before barrier for latency)
    unsigned vv[2][8];
    #pragma unroll
    for (int n2 = 0; n2 < 2; ++n2) {
      int key0 = (w + n2 * 4) * 8;
      #pragma unroll
      for (int e = 0; e < 8; ++e)
        vv[n2][e] = *(const unsigned*)&V[slab + (size_t)(it * 64 + key0 + e) * 128 + vd0];
    }
    __syncthreads();                       // B1: prev iter's LDS readers done
    // V transpose stores (swizzled [128][64]; conflict-free)
    {
      int swz = (lane & 7) << 3;           // ((vd0>>1)&7)<<3, vd0 even
      #pragma unroll
      for (int n2 = 0; n2 < 2; ++n2) {
        int key0 = (w + n2 * 4) * 8;
        u16x8 lo, hi;
        #pragma unroll
        for (int e = 0; e < 8; ++e) {
          lo[e] = (u16)(vv[n2][e] & 0xffffu);
          hi[e] = (u16)(vv[n2][e] >> 16);
        }
        *(u16x8*)&Vlds[vd0 * 64 + (key0 ^ swz)] = lo;
        *(u16x8*)&Vlds[(vd0 + 1) * 64 + (key0 ^ swz)] = hi;
      }
    }
    __syncthreads();                       // B2: V visible; K[it] drained (cheap)

    // S = Q K^T  (raw dot products; scale folded into softmax)
    f32x4 sa[2][4];
    #pragma unroll
    for (int i = 0; i < 2; ++i)
      #pragma unroll
      for (int j = 0; j < 4; ++j) sa[i][j] = (f32x4){0.f, 0.f, 0.f, 0.f};
    #pragma unroll
    for (int kc = 0; kc < 4; ++kc) {
      bf16x8 bk[4];
      #pragma unroll
      for (int ni = 0; ni < 4; ++ni) {
        int krow = ni * 16 + ln;
        bk[ni] = *(const bf16x8*)&Klds[krow * 128 +
                                       ((kc * 32 + qd * 8) ^ ((krow & 7) << 3))];
      }
      #pragma unroll
      for (int mi = 0; mi < 2; ++mi)
        #pragma unroll
        for (int ni = 0; ni < 4; ++ni)
          sa[mi][ni] = mfma16(aq[mi][kc], bk[ni], sa[mi][ni]);
    }

    // online softmax per q-row; row r of tile lives on one quad (16 lanes)
    #pragma unroll
    for (int mi = 0; mi < 2; ++mi) {
      #pragma unroll
      for (int r = 0; r < 4; ++r) {
        float tmax = -1e30f;
        #pragma unroll
        for (int ni = 0; ni < 4; ++ni) tmax = fmaxf(tmax, sa[mi][ni][r]);
        tmax *= SC;
        tmax = fmaxf(tmax, __shfl_xor(tmax, 1));
        tmax = fmaxf(tmax, __shfl_xor(tmax, 2));
        tmax = fmaxf(tmax, __shfl_xor(tmax, 4));
        tmax = fmaxf(tmax, __shfl_xor(tmax, 8));
        float mnew = fmaxf(mst[mi][r], tmax);
        float alpha = exp2f(mst[mi][r] - mnew);
        float p[4], rs = 0.f;
        #pragma unroll
        for (int ni = 0; ni < 4; ++ni) {
          p[ni] = exp2f(sa[mi][ni][r] * SC - mnew);
          rs += p[ni];
        }
        lsum[mi][r] = lsum[mi][r] * alpha + rs;  // per-lane partial
        mst[mi][r] = mnew;
        #pragma unroll
        for (int di = 0; di < 8; ++di) o[mi][di][r] *= alpha;
        #pragma unroll
        for (int ni = 0; ni < 4; ++ni)     // P in A-operand layout [q][key]
          Plds[(w * 32 + mi * 16 + qd * 4 + r) * 72 + ni * 16 + ln] = f2bf(p[ni]);
      }
    }

    __syncthreads();                       // B3: P visible; QK^T reads drained

    // early K[it+1] prefetch: Klds overwrite safe after B3; in flight
    // across PV + next V-loads + B1 + V-stores, drained at next B2
    if (it < 31) {
      #pragma unroll
      for (int j = 0; j < 4; ++j) {
        int oe = j * 2048 + w * 512 + lane * 8;
        int se = oe ^ (((oe >> 7) & 7) << 3);
        async16(&Kb[slab + (size_t)(it + 1) * 8192 + se],
                &Klds[j * 2048 + w * 512]);
      }
    }

    // O += P V
    #pragma unroll
    for (int kc = 0; kc < 2; ++kc) {
      bf16x8 ap[2];
      #pragma unroll
      for (int mi = 0; mi < 2; ++mi)
        ap[mi] = *(const bf16x8*)&Plds[(w * 32 + mi * 16 + ln) * 72 + kc * 32 + qd * 8];
      #pragma unroll
      for (int di = 0; di < 8; ++di) {
        int vrow = di * 16 + ln;
        bf16x8 bv = *(const bf16x8*)&Vlds[vrow * 64 +
                         ((kc * 32 + qd * 8) ^ (((vrow >> 1) & 7) << 3))];
        o[0][di] = mfma16(ap[0], bv, o[0][di]);
        o[1][di] = mfma16(ap[1], bv, o[1][di]);
      }
    }
  }

  // epilogue: reduce per-lane lsum across the quad, normalize, write out
  #pragma unroll
  for (int mi = 0; mi < 2; ++mi) {
    #pragma unroll
    for (int r = 0; r < 4; ++r) {
      float l = lsum[mi][r];
      l += __shfl_xor(l, 1);
      l += __shfl_xor(l, 2);
      l += __shfl_xor(l, 4);
      l += __shfl_xor(l, 8);
      float inv = 1.0f / l;
      int lrow = qt * 128 + w * 32 + mi * 16 + qd * 4 + r;
      size_t orow = ((size_t)b * L_ + lrow) * DIM_ + (size_t)h * HD_;
      #pragma unroll
      for (int di = 0; di < 8; ++di)
        Ao[orow + di * 16 + ln] = f2bf(o[mi][di][r] * inv);
    }
  }
}

// ---------------------------------------------------------------------------
extern "C" void kernel_launch(void* const* d_in, const int* in_sizes, int n_in,
                              void* d_out, int out_size, void* d_ws, size_t ws_size,
                              hipStream_t stream) {
  const float* x    = (const float*)d_in[0];
  const float* cs   = (const float*)d_in[1];
  const float* sn   = (const float*)d_in[2];
  const float* wqkv = (const float*)d_in[3];
  const float* wout = (const float*)d_in[4];
  const float* bias = (const float*)d_in[5];
  u16* ws = (u16*)d_ws;

  // Workspace (u16 elems), 92.3 MB total with two time-multiplexed overlaps:
  //   wqkvT 12,582,912  (N=6144 x K=2048 bf16; REUSED for woutT after gemm1)
  //   xbfAo  8,388,608  (x_bf during gemm1; Ao after attn)
  //   Qb/Kbuf/Vbuf 3 x 8,388,608
  u16* wqkvT = ws;
  u16* woutT = ws;                        // same region, written after gemm1
  u16* xbfAo = wqkvT + 12582912;
  u16* Qb    = xbfAo + 8388608;
  u16* Kbuf  = Qb + 8388608;
  u16* Vbuf  = Kbuf + 8388608;

  cvt_bf16<<<dim3(8192), 256, 0, stream>>>(x, xbfAo);
  transpose_cvt<<<dim3(96, 32), 256, 0, stream>>>(wqkv, wqkvT, 2048, 6144);
  gemm_bt<1><<<dim3(48, 32), 256, 0, stream>>>(
      xbfAo, wqkvT, Qb, Kbuf, Vbuf, nullptr, nullptr, M_, NQKV_, DIM_);
  transpose_cvt<<<dim3(32, 32), 256, 0, stream>>>(wout, woutT, 2048, 2048);
  rotary_k<<<dim3(8192), 256, 0, stream>>>(Qb, Kbuf, cs, sn);
  attn_k<<<dim3(16, 32), 256, 0, stream>>>(Qb, Kbuf, Vbuf, xbfAo);
  gemm_bt<2><<<dim3(16, 32), 256, 0, stream>>>(
      xbfAo, woutT, nullptr, nullptr, nullptr, bias, (float*)d_out, M_, DIM_, DIM_);
}

// Round 14
// 469.654 us; speedup vs baseline: 1.0212x; 1.0212x over previous
//
#include <hip/hip_runtime.h>
#include <cstdint>
#include <cstddef>

typedef unsigned short u16;
typedef __attribute__((ext_vector_type(2))) unsigned short u16x2;
typedef __attribute__((ext_vector_type(4))) unsigned short u16x4;
typedef __attribute__((ext_vector_type(8))) unsigned short u16x8;
typedef __attribute__((ext_vector_type(4))) float f32x4;
typedef __attribute__((ext_vector_type(8))) __bf16 bf16x8;

#define B_    2
#define L_    2048
#define DIM_  2048
#define H_    16
#define HD_   128
#define NQKV_ 6144
#define M_    4096   // B_*L_

__device__ __forceinline__ float b2f(u16 h) {
  union { unsigned u; float f; } v; v.u = ((unsigned)h) << 16; return v.f;
}
__device__ __forceinline__ u16 f2bf(float f) {
  unsigned u = __float_as_uint(f);
  u += 0x7fffu + ((u >> 16) & 1u);   // RNE
  return (u16)(u >> 16);
}
__device__ __forceinline__ f32x4 mfma16(bf16x8 a, bf16x8 b, f32x4 c) {
  return __builtin_amdgcn_mfma_f32_16x16x32_bf16(a, b, c, 0, 0, 0);
}
__device__ __forceinline__ void async16(const void* g, void* l) {
  __builtin_amdgcn_global_load_lds(
      (const __attribute__((address_space(1))) unsigned*)g,
      (__attribute__((address_space(3))) unsigned*)l, 16, 0, 0);
}

// ---------------------------------------------------------------------------
// Merged pre-pass (saves one launch): blocks < 8192 do the straight
// f32->bf16 convert of x (4 elems/thread); blocks >= 8192 transpose+convert
// wqkv (2048 x 6144 f32) -> wqkvT (6144 x 2048 bf16) via a 64x64 LDS tile.
// Branch is block-uniform; the two halves touch disjoint memory.
// ---------------------------------------------------------------------------
__global__ __launch_bounds__(256) void prepass_k(
    const float* __restrict__ x, u16* __restrict__ xbf,
    const float* __restrict__ wqkv, u16* __restrict__ wqkvT) {
  __shared__ u16 tile[64][66];
  const int bid = blockIdx.x;
  if (bid < 8192) {
    int i = (bid * 256 + threadIdx.x) * 4;
    f32x4 v = *(const f32x4*)&x[i];
    u16x4 o;
    #pragma unroll
    for (int j = 0; j < 4; ++j) o[j] = f2bf(v[j]);
    *(u16x4*)&xbf[i] = o;
  } else {
    const int t = bid - 8192;            // 96 x 32 tile grid (C=6144, R=2048)
    const int by = t / 96, bx = t - by * 96;
    const int r0 = by * 64, c0 = bx * 64;
    const int R = 2048, C = 6144;
    #pragma unroll
    for (int i = 0; i < 16; ++i) {
      int f = i * 256 + threadIdx.x;
      int r = f >> 6, c = f & 63;
      tile[r][c] = f2bf(wqkv[(size_t)(r0 + r) * C + (c0 + c)]);
    }
    __syncthreads();
    #pragma unroll
    for (int i = 0; i < 8; ++i) {
      int f = i * 256 + threadIdx.x;
      int cr = f >> 5, rp = (f & 31) * 2;
      u16x2 v = {tile[rp][cr], tile[rp + 1][cr]};
      *(u16x2*)&wqkvT[(size_t)(c0 + cr) * R + (r0 + rp)] = v;
    }
  }
}

// ---------------------------------------------------------------------------
// Merged post-gemm1 pass (saves one launch): blocks < 1024 transpose+convert
// wout (2048 x 2048 f32) -> woutT (bf16); blocks >= 1024 apply in-place
// rotary to Q and K (INTERLEAVED-PAIR layout: pos 2d = x1(d), 2d+1 = x2(d)).
// Rotary is fully vectorized: one u16x8 load + f32x4 cos/sin + u16x8 store.
// Both halves depend only on gemm1 completion; disjoint memory.
// ---------------------------------------------------------------------------
__global__ __launch_bounds__(256) void post_k(
    const float* __restrict__ wout, u16* __restrict__ woutT,
    u16* __restrict__ Q, u16* __restrict__ Kb,
    const float* __restrict__ cs, const float* __restrict__ sn) {
  __shared__ u16 tile[64][66];
  const int bid = blockIdx.x;
  if (bid < 1024) {                      // 32 x 32 tile grid (C=R=2048)
    const int bx = bid & 31, by = bid >> 5;
    const int r0 = by * 64, c0 = bx * 64;
    const int R = 2048, C = 2048;
    #pragma unroll
    for (int i = 0; i < 16; ++i) {
      int f = i * 256 + threadIdx.x;
      int r = f >> 6, c = f & 63;
      tile[r][c] = f2bf(wout[(size_t)(r0 + r) * C + (c0 + c)]);
    }
    __syncthreads();
    #pragma unroll
    for (int i = 0; i < 8; ++i) {
      int f = i * 256 + threadIdx.x;
      int cr = f >> 5, rp = (f & 31) * 2;
      u16x2 v = {tile[rp][cr], tile[rp + 1][cr]};
      *(u16x2*)&woutT[(size_t)(c0 + cr) * R + (r0 + rp)] = v;
    }
  } else {
    const int rb = bid - 1024;           // rotary: 8 rows/block, 2 tensors
    const int tid = threadIdx.x;
    const int tensor = tid >> 7;         // 0 = Q, 1 = K
    const int rsub = (tid >> 4) & 7;
    const int j = tid & 15;
    const int row = rb * 8 + rsub;       // flat (bh*L + l)
    const int l = row & (L_ - 1);
    u16* P = tensor ? Kb : Q;
    size_t base = (size_t)row * HD_ + j * 8;
    u16x8 v = *(const u16x8*)&P[base];
    f32x4 c = *(const f32x4*)&cs[l * 64 + j * 4];
    f32x4 s = *(const f32x4*)&sn[l * 64 + j * 4];
    u16x8 o;
    #pragma unroll
    for (int e = 0; e < 4; ++e) {
      float x1 = b2f(v[2 * e]), x2 = b2f(v[2 * e + 1]);
      o[2 * e]     = f2bf(x1 * c[e] - x2 * s[e]);
      o[2 * e + 1] = f2bf(x2 * c[e] + x1 * s[e]);
    }
    *(u16x8*)&P[base] = o;
  }
}

// ---------------------------------------------------------------------------
// m97-style GEMM, BK=64 (round-12, proven −27 us): C[M,N] = A*Bt^T, bf16,
// async16 staging, 128x128 tile, 256 thr. BK=64 halves barrier count;
// LDS 32 KB. Tiles XOR-swizzled (elem = row*64 + (col ^ ((row&7)<<3)))
// via inverse-swizzled global source (rule #21); post-swizzle bank group
// (kk*4+qd)^(ln&7) = 8 lanes/group = b128 minimum.
// MODE 1: scatter epilogue into Q/K/V; t/h/b hoisted; Q/K interleaved-pair.
// MODE 2: bias-add epilogue, f32 row-major store.
// ---------------------------------------------------------------------------
template <int MODE>
__global__ __launch_bounds__(256) void gemm_bt(
    const u16* __restrict__ A, const u16* __restrict__ Bt,
    u16* __restrict__ D0, u16* __restrict__ D1, u16* __restrict__ D2,
    const float* __restrict__ bias, float* __restrict__ outp,
    int M, int N, int K) {
  __shared__ __align__(16) u16 Alds[128 * 64];
  __shared__ __align__(16) u16 Blds[128 * 64];
  const int tid = threadIdx.x;
  const int wave = tid >> 6;
  const int wm = wave >> 1, wn = wave & 1;
  const int ln = tid & 15, qd = (tid >> 4) & 3;
  const int m0 = blockIdx.y * 128, n0 = blockIdx.x * 128;

  f32x4 acc[4][4];
  #pragma unroll
  for (int i = 0; i < 4; ++i)
    #pragma unroll
    for (int j = 0; j < 4; ++j) acc[i][j] = (f32x4){0.f, 0.f, 0.f, 0.f};

  for (int k0 = 0; k0 < K; k0 += 64) {
    __syncthreads();                     // prev iter's fragment ds_reads done
    #pragma unroll
    for (int j = 0; j < 4; ++j) {
      int oe = j * 2048 + tid * 8;       // linear LDS elem offset (128x64)
      int se = oe ^ (((oe >> 6) & 7) << 3);  // swizzled source elem
      int r = oe >> 6, c = se & 63;
      async16(&A[(size_t)(m0 + r) * K + (k0 + c)], &Alds[j * 2048 + wave * 512]);
      async16(&Bt[(size_t)(n0 + r) * K + (k0 + c)], &Blds[j * 2048 + wave * 512]);
    }
    __syncthreads();                     // drains vmcnt before use
    #pragma unroll
    for (int kk = 0; kk < 2; ++kk) {     // two 32-wide K-slices
      bf16x8 af[4], bfr[4];
      #pragma unroll
      for (int mi = 0; mi < 4; ++mi) {
        int arow = wm * 64 + mi * 16 + ln;
        af[mi] = *(const bf16x8*)&Alds[arow * 64 +
                     ((kk * 32 + qd * 8) ^ ((arow & 7) << 3))];
      }
      #pragma unroll
      for (int ni = 0; ni < 4; ++ni) {
        int brow = wn * 64 + ni * 16 + ln;
        bfr[ni] = *(const bf16x8*)&Blds[brow * 64 +
                     ((kk * 32 + qd * 8) ^ ((brow & 7) << 3))];
      }
      #pragma unroll
      for (int mi = 0; mi < 4; ++mi)
        #pragma unroll
        for (int ni = 0; ni < 4; ++ni)
          acc[mi][ni] = mfma16(af[mi], bfr[ni], acc[mi][ni]);
    }
  }

  // epilogue: C/D layout col=lane&15, row=quad*4+reg  [m89-verified]
  if (MODE == 2) {
    #pragma unroll
    for (int mi = 0; mi < 4; ++mi)
      #pragma unroll
      for (int ni = 0; ni < 4; ++ni)
        #pragma unroll
        for (int r = 0; r < 4; ++r) {
          int row = m0 + wm * 64 + mi * 16 + qd * 4 + r;
          int col = n0 + wn * 64 + ni * 16 + ln;
          outp[(size_t)row * N + col] = acc[mi][ni][r] + bias[col];
        }
  } else {
    const int t  = n0 >> 11;             // 0=q, 1=k, 2=v   (block-uniform)
    const int hh = (n0 & 2047) >> 7;     // head            (block-uniform)
    const int bb = m0 >> 11;             // batch           (block-uniform)
    const int l0 = (m0 & 2047) + wm * 64;
    // Q/K (t<2): interleaved-pair pos = ((ln+ni*16)<<1)|wn; V natural.
    const int d0    = (t != 2) ? (((ln) << 1) | wn) : (wn * 64 + ln);
    const int dstep = (t != 2) ? 32 : 16;
    u16* dst = (t == 0) ? D0 : ((t == 1) ? D1 : D2);
    u16* basep = dst + ((size_t)(bb * H_ + hh) * L_) * HD_;
    #pragma unroll
    for (int mi = 0; mi < 4; ++mi)
      #pragma unroll
      for (int r = 0; r < 4; ++r) {
        int l = l0 + mi * 16 + qd * 4 + r;
        #pragma unroll
        for (int ni = 0; ni < 4; ++ni)
          basep[(size_t)l * HD_ + d0 + ni * dstep] = f2bf(acc[mi][ni][r]);
      }
  }
}

// ---------------------------------------------------------------------------
// Flash attention. grid (16 qtiles, 32 bh), 256 thr (4 waves).
// Q,K,V all (B*H, L, 128) bf16. BM=128, BN=64 keys/iter.
//
// ROUND-12 EXACT (proven 168.0 us, 116 VGPR, 21% occupancy — protected
// baseline). In-block pipelining is conclusively dead here:
//   r4 (dbuf+fences): 290 us; r8 (fences): 240 us; r13 (early prefetch,
//   no fences, VGPR 128): 175 us. Cross-block overlap at 3 blocks/CU
//   already hides the barrier drains; every restructure only adds cost.
// Session rules (rounds 4-13):
//  - VGPR <= 128 or occupancy halves (64-granular quantum).
//  - NO sched_barrier/inline-asm fences (pin live ranges, +24 VGPR).
//  - NO defer-max branch (+24 VGPR).
//  - attn is NOT memory-bound (r11: FETCH 139->25 MB cost 11 us).
//
// LDS swizzles (both-sides, rule #21):
//   K/Q tiles: elem = row*128 + (col ^ ((row&7)<<3)); staged via inverse-
//     swizzled GLOBAL source (global_load_lds writes LDS linearly).
//   Vlds [128][64]: elem = row*64 + (col ^ (((row>>1)&7)<<3)).
//   Plds stride-72. LDS = 50 KB -> 3 blocks/CU.
// Deferred l-reduce: lsum kept PER-LANE, quad-reduced once in epilogue.
// ---------------------------------------------------------------------------
__global__ __launch_bounds__(256, 4) void attn_k(
    const u16* __restrict__ Q, const u16* __restrict__ Kb,
    const u16* __restrict__ V, u16* __restrict__ Ao) {
  __shared__ __align__(16) u16 lds[25600];     // 50 KB
  u16* Klds = lds;               // [64 keys][128 d]  (swizzled)
  u16* Vlds = lds + 8192;        // [128 d][64 keys]  (swizzled)
  u16* Plds = lds + 16384;       // [128 q][72], keys 0..63 used
  const int tid = threadIdx.x;
  const int w = tid >> 6, lane = tid & 63;
  const int ln = lane & 15, qd = lane >> 4;
  const int qt = blockIdx.x, bh = blockIdx.y;
  const int b = bh >> 4, h = bh & 15;
  const size_t slab = (size_t)bh * (L_ * HD_);
  const int vd0 = 2 * lane;                    // V staging: d-pair

  // stage Q tile (contiguous 32 KB, overlays K+V) via async16, pre-swizzled
  #pragma unroll
  for (int j = 0; j < 8; ++j) {
    int oe = j * 2048 + w * 512 + lane * 8;        // linear LDS elem offset
    int se = oe ^ (((oe >> 7) & 7) << 3);          // swizzled global source
    async16(&Q[slab + (size_t)qt * 16384 + se], &lds[j * 2048 + w * 512]);
  }
  __syncthreads();
  bf16x8 aq[2][4];                         // Q fragments in registers
  #pragma unroll
  for (int mi = 0; mi < 2; ++mi) {
    int qrow = w * 32 + mi * 16 + ln;
    #pragma unroll
    for (int kc = 0; kc < 4; ++kc)
      aq[mi][kc] = *(const bf16x8*)&lds[qrow * 128 +
                                        ((kc * 32 + qd * 8) ^ ((qrow & 7) << 3))];
  }

  f32x4 o[2][8];
  #pragma unroll
  for (int i = 0; i < 2; ++i)
    #pragma unroll
    for (int j = 0; j < 8; ++j) o[i][j] = (f32x4){0.f, 0.f, 0.f, 0.f};
  float mst[2][4], lsum[2][4];             // lsum = PER-LANE partial sum
  #pragma unroll
  for (int i = 0; i < 2; ++i)
    #pragma unroll
    for (int r = 0; r < 4; ++r) { mst[i][r] = -1e30f; lsum[i][r] = 0.f; }
  const float SC = 0.12751744f;            // (1/sqrt(128)) * log2(e)

  for (int it = 0; it < 32; ++it) {
    // V global loads -> regs (no LDS touch; before barrier for latency)
    unsigned vv[2][8];
    #pragma unroll
    for (int n2 = 0; n2 < 2; ++n2) {
      int key0 = (w + n2 * 4) * 8;
      #pragma unroll
      for (int e = 0; e < 8; ++e)
        vv[n2][e] = *(const unsigned*)&V[slab + (size_t)(it * 64 + key0 + e) * 128 + vd0];
    }
    __syncthreads();                       // B1: prev iter's LDS readers done
    // K tile via async16, source pre-swizzled (see header comment)
    #pragma unroll
    for (int j = 0; j < 4; ++j) {
      int oe = j * 2048 + w * 512 + lane * 8;
      int se = oe ^ (((oe >> 7) & 7) << 3);
      async16(&Kb[slab + (size_t)it * 8192 + se], &Klds[j * 2048 + w * 512]);
    }
    // V transpose stores (swizzled [128][64]; conflict-free, see header)
    {
      int swz = (lane & 7) << 3;           // ((vd0>>1)&7)<<3, vd0 even
      #pragma unroll
      for (int n2 = 0; n2 < 2; ++n2) {
        int key0 = (w + n2 * 4) * 8;
        u16x8 lo, hi;
        #pragma unroll
        for (int e = 0; e < 8; ++e) {
          lo[e] = (u16)(vv[n2][e] & 0xffffu);
          hi[e] = (u16)(vv[n2][e] >> 16);
        }
        *(u16x8*)&Vlds[vd0 * 64 + (key0 ^ swz)] = lo;
        *(u16x8*)&Vlds[(vd0 + 1) * 64 + (key0 ^ swz)] = hi;
      }
    }
    __syncthreads();                       // B2: drains vmcnt (K) + lgkm (V)

    // S = Q K^T  (raw dot products; scale folded into softmax)
    f32x4 sa[2][4];
    #pragma unroll
    for (int i = 0; i < 2; ++i)
      #pragma unroll
      for (int j = 0; j < 4; ++j) sa[i][j] = (f32x4){0.f, 0.f, 0.f, 0.f};
    #pragma unroll
    for (int kc = 0; kc < 4; ++kc) {
      bf16x8 bk[4];
      #pragma unroll
      for (int ni = 0; ni < 4; ++ni) {
        int krow = ni * 16 + ln;
        bk[ni] = *(const bf16x8*)&Klds[krow * 128 +
                                       ((kc * 32 + qd * 8) ^ ((krow & 7) << 3))];
      }
      #pragma unroll
      for (int mi = 0; mi < 2; ++mi)
        #pragma unroll
        for (int ni = 0; ni < 4; ++ni)
          sa[mi][ni] = mfma16(aq[mi][kc], bk[ni], sa[mi][ni]);
    }

    // online softmax per q-row; row r of tile lives on one quad (16 lanes)
    #pragma unroll
    for (int mi = 0; mi < 2; ++mi) {
      #pragma unroll
      for (int r = 0; r < 4; ++r) {
        float tmax = -1e30f;
        #pragma unroll
        for (int ni = 0; ni < 4; ++ni) tmax = fmaxf(tmax, sa[mi][ni][r]);
        tmax *= SC;
        tmax = fmaxf(tmax, __shfl_xor(tmax, 1));
        tmax = fmaxf(tmax, __shfl_xor(tmax, 2));
        tmax = fmaxf(tmax, __shfl_xor(tmax, 4));
        tmax = fmaxf(tmax, __shfl_xor(tmax, 8));
        float mnew = fmaxf(mst[mi][r], tmax);
        float alpha = exp2f(mst[mi][r] - mnew);
        float p[4], rs = 0.f;
        #pragma unroll
        for (int ni = 0; ni < 4; ++ni) {
          p[ni] = exp2f(sa[mi][ni][r] * SC - mnew);
          rs += p[ni];
        }
        lsum[mi][r] = lsum[mi][r] * alpha + rs;  // per-lane partial
        mst[mi][r] = mnew;
        #pragma unroll
        for (int di = 0; di < 8; ++di) o[mi][di][r] *= alpha;
        #pragma unroll
        for (int ni = 0; ni < 4; ++ni)     // P in A-operand layout [q][key]
          Plds[(w * 32 + mi * 16 + qd * 4 + r) * 72 + ni * 16 + ln] = f2bf(p[ni]);
      }
    }

    __syncthreads();                       // B3: P writes visible

    // O += P V
    #pragma unroll
    for (int kc = 0; kc < 2; ++kc) {
      bf16x8 ap[2];
      #pragma unroll
      for (int mi = 0; mi < 2; ++mi)
        ap[mi] = *(const bf16x8*)&Plds[(w * 32 + mi * 16 + ln) * 72 + kc * 32 + qd * 8];
      #pragma unroll
      for (int di = 0; di < 8; ++di) {
        int vrow = di * 16 + ln;
        bf16x8 bv = *(const bf16x8*)&Vlds[vrow * 64 +
                         ((kc * 32 + qd * 8) ^ (((vrow >> 1) & 7) << 3))];
        o[0][di] = mfma16(ap[0], bv, o[0][di]);
        o[1][di] = mfma16(ap[1], bv, o[1][di]);
      }
    }
  }

  // epilogue: reduce per-lane lsum across the quad, normalize, write out
  #pragma unroll
  for (int mi = 0; mi < 2; ++mi) {
    #pragma unroll
    for (int r = 0; r < 4; ++r) {
      float l = lsum[mi][r];
      l += __shfl_xor(l, 1);
      l += __shfl_xor(l, 2);
      l += __shfl_xor(l, 4);
      l += __shfl_xor(l, 8);
      float inv = 1.0f / l;
      int lrow = qt * 128 + w * 32 + mi * 16 + qd * 4 + r;
      size_t orow = ((size_t)b * L_ + lrow) * DIM_ + (size_t)h * HD_;
      #pragma unroll
      for (int di = 0; di < 8; ++di)
        Ao[orow + di * 16 + ln] = f2bf(o[mi][di][r] * inv);
    }
  }
}

// ---------------------------------------------------------------------------
extern "C" void kernel_launch(void* const* d_in, const int* in_sizes, int n_in,
                              void* d_out, int out_size, void* d_ws, size_t ws_size,
                              hipStream_t stream) {
  const float* x    = (const float*)d_in[0];
  const float* cs   = (const float*)d_in[1];
  const float* sn   = (const float*)d_in[2];
  const float* wqkv = (const float*)d_in[3];
  const float* wout = (const float*)d_in[4];
  const float* bias = (const float*)d_in[5];
  u16* ws = (u16*)d_ws;

  // Workspace (u16 elems), 92.3 MB total with two time-multiplexed overlaps:
  //   wqkvT 12,582,912  (N=6144 x K=2048 bf16; REUSED for woutT after gemm1)
  //   xbfAo  8,388,608  (x_bf during gemm1; Ao after attn)
  //   Qb/Kbuf/Vbuf 3 x 8,388,608
  u16* wqkvT = ws;
  u16* woutT = ws;                        // same region, written after gemm1
  u16* xbfAo = wqkvT + 12582912;
  u16* Qb    = xbfAo + 8388608;
  u16* Kbuf  = Qb + 8388608;
  u16* Vbuf  = Kbuf + 8388608;

  // 5 launches (was 7): cvt+wqkv-transpose merged; wout-transpose+rotary merged
  prepass_k<<<dim3(11264), 256, 0, stream>>>(x, xbfAo, wqkv, wqkvT);
  gemm_bt<1><<<dim3(48, 32), 256, 0, stream>>>(
      xbfAo, wqkvT, Qb, Kbuf, Vbuf, nullptr, nullptr, M_, NQKV_, DIM_);
  post_k<<<dim3(9216), 256, 0, stream>>>(wout, woutT, Qb, Kbuf, cs, sn);
  attn_k<<<dim3(16, 32), 256, 0, stream>>>(Qb, Kbuf, Vbuf, xbfAo);
  gemm_bt<2><<<dim3(16, 32), 256, 0, stream>>>(
      xbfAo, woutT, nullptr, nullptr, nullptr, bias, (float*)d_out, M_, DIM_, DIM_);
}

// Round 15
// 449.052 us; speedup vs baseline: 1.0681x; 1.0459x over previous
//
#include <hip/hip_runtime.h>
#include <cstdint>
#include <cstddef>

typedef unsigned short u16;
typedef __attribute__((ext_vector_type(2))) unsigned short u16x2;
typedef __attribute__((ext_vector_type(4))) unsigned short u16x4;
typedef __attribute__((ext_vector_type(8))) unsigned short u16x8;
typedef __attribute__((ext_vector_type(4))) float f32x4;
typedef __attribute__((ext_vector_type(8))) __bf16 bf16x8;

#define B_    2
#define L_    2048
#define DIM_  2048
#define H_    16
#define HD_   128
#define NQKV_ 6144
#define M_    4096   // B_*L_

__device__ __forceinline__ float b2f(u16 h) {
  union { unsigned u; float f; } v; v.u = ((unsigned)h) << 16; return v.f;
}
__device__ __forceinline__ u16 f2bf(float f) {
  unsigned u = __float_as_uint(f);
  u += 0x7fffu + ((u >> 16) & 1u);   // RNE
  return (u16)(u >> 16);
}
__device__ __forceinline__ f32x4 mfma16(bf16x8 a, bf16x8 b, f32x4 c) {
  return __builtin_amdgcn_mfma_f32_16x16x32_bf16(a, b, c, 0, 0, 0);
}
__device__ __forceinline__ void async16(const void* g, void* l) {
  __builtin_amdgcn_global_load_lds(
      (const __attribute__((address_space(1))) unsigned*)g,
      (__attribute__((address_space(3))) unsigned*)l, 16, 0, 0);
}

// ---------------------------------------------------------------------------
// Merged pre-pass: blocks < 8192 do the straight f32->bf16 convert of x
// (4 elems/thread); blocks >= 8192 transpose+convert wqkv (2048 x 6144 f32)
// -> wqkvT (6144 x 2048 bf16) via a 64x64 LDS tile. Block-uniform branch.
// ---------------------------------------------------------------------------
__global__ __launch_bounds__(256) void prepass_k(
    const float* __restrict__ x, u16* __restrict__ xbf,
    const float* __restrict__ wqkv, u16* __restrict__ wqkvT) {
  __shared__ u16 tile[64][66];
  const int bid = blockIdx.x;
  if (bid < 8192) {
    int i = (bid * 256 + threadIdx.x) * 4;
    f32x4 v = *(const f32x4*)&x[i];
    u16x4 o;
    #pragma unroll
    for (int j = 0; j < 4; ++j) o[j] = f2bf(v[j]);
    *(u16x4*)&xbf[i] = o;
  } else {
    const int t = bid - 8192;            // 96 x 32 tile grid (C=6144, R=2048)
    const int by = t / 96, bx = t - by * 96;
    const int r0 = by * 64, c0 = bx * 64;
    const int R = 2048, C = 6144;
    #pragma unroll
    for (int i = 0; i < 16; ++i) {
      int f = i * 256 + threadIdx.x;
      int r = f >> 6, c = f & 63;
      tile[r][c] = f2bf(wqkv[(size_t)(r0 + r) * C + (c0 + c)]);
    }
    __syncthreads();
    #pragma unroll
    for (int i = 0; i < 8; ++i) {
      int f = i * 256 + threadIdx.x;
      int cr = f >> 5, rp = (f & 31) * 2;
      u16x2 v = {tile[rp][cr], tile[rp + 1][cr]};
      *(u16x2*)&wqkvT[(size_t)(c0 + cr) * R + (r0 + rp)] = v;
    }
  }
}

// ---------------------------------------------------------------------------
// Merged post-gemm1 pass: blocks < 1024 transpose+convert wout (2048x2048
// f32) -> woutT (bf16); blocks >= 1024 apply in-place rotary to Q and K
// (INTERLEAVED-PAIR layout: pos 2d = x1(d), 2d+1 = x2(d)); fully vectorized.
// ---------------------------------------------------------------------------
__global__ __launch_bounds__(256) void post_k(
    const float* __restrict__ wout, u16* __restrict__ woutT,
    u16* __restrict__ Q, u16* __restrict__ Kb,
    const float* __restrict__ cs, const float* __restrict__ sn) {
  __shared__ u16 tile[64][66];
  const int bid = blockIdx.x;
  if (bid < 1024) {                      // 32 x 32 tile grid (C=R=2048)
    const int bx = bid & 31, by = bid >> 5;
    const int r0 = by * 64, c0 = bx * 64;
    const int R = 2048, C = 2048;
    #pragma unroll
    for (int i = 0; i < 16; ++i) {
      int f = i * 256 + threadIdx.x;
      int r = f >> 6, c = f & 63;
      tile[r][c] = f2bf(wout[(size_t)(r0 + r) * C + (c0 + c)]);
    }
    __syncthreads();
    #pragma unroll
    for (int i = 0; i < 8; ++i) {
      int f = i * 256 + threadIdx.x;
      int cr = f >> 5, rp = (f & 31) * 2;
      u16x2 v = {tile[rp][cr], tile[rp + 1][cr]};
      *(u16x2*)&woutT[(size_t)(c0 + cr) * R + (r0 + rp)] = v;
    }
  } else {
    const int rb = bid - 1024;           // rotary: 8 rows/block, 2 tensors
    const int tid = threadIdx.x;
    const int tensor = tid >> 7;         // 0 = Q, 1 = K
    const int rsub = (tid >> 4) & 7;
    const int j = tid & 15;
    const int row = rb * 8 + rsub;       // flat (bh*L + l)
    const int l = row & (L_ - 1);
    u16* P = tensor ? Kb : Q;
    size_t base = (size_t)row * HD_ + j * 8;
    u16x8 v = *(const u16x8*)&P[base];
    f32x4 c = *(const f32x4*)&cs[l * 64 + j * 4];
    f32x4 s = *(const f32x4*)&sn[l * 64 + j * 4];
    u16x8 o;
    #pragma unroll
    for (int e = 0; e < 4; ++e) {
      float x1 = b2f(v[2 * e]), x2 = b2f(v[2 * e + 1]);
      o[2 * e]     = f2bf(x1 * c[e] - x2 * s[e]);
      o[2 * e + 1] = f2bf(x2 * c[e] + x1 * s[e]);
    }
    *(u16x8*)&P[base] = o;
  }
}

// ---------------------------------------------------------------------------
// m97-style GEMM, BK=64 (round-12, proven −27 us): C[M,N] = A*Bt^T, bf16,
// async16 staging, 128x128 tile, 256 thr. BK=64 halves barrier count;
// LDS 32 KB. Tiles XOR-swizzled (elem = row*64 + (col ^ ((row&7)<<3)))
// via inverse-swizzled global source (rule #21); post-swizzle bank group
// (kk*4+qd)^(ln&7) = 8 lanes/group = b128 minimum.
// MODE 1: scatter epilogue into Q/K/V; t/h/b hoisted; Q/K interleaved-pair.
// MODE 2: bias-add epilogue, f32 row-major store.
// ---------------------------------------------------------------------------
template <int MODE>
__global__ __launch_bounds__(256) void gemm_bt(
    const u16* __restrict__ A, const u16* __restrict__ Bt,
    u16* __restrict__ D0, u16* __restrict__ D1, u16* __restrict__ D2,
    const float* __restrict__ bias, float* __restrict__ outp,
    int M, int N, int K) {
  __shared__ __align__(16) u16 Alds[128 * 64];
  __shared__ __align__(16) u16 Blds[128 * 64];
  const int tid = threadIdx.x;
  const int wave = tid >> 6;
  const int wm = wave >> 1, wn = wave & 1;
  const int ln = tid & 15, qd = (tid >> 4) & 3;
  const int m0 = blockIdx.y * 128, n0 = blockIdx.x * 128;

  f32x4 acc[4][4];
  #pragma unroll
  for (int i = 0; i < 4; ++i)
    #pragma unroll
    for (int j = 0; j < 4; ++j) acc[i][j] = (f32x4){0.f, 0.f, 0.f, 0.f};

  for (int k0 = 0; k0 < K; k0 += 64) {
    __syncthreads();                     // prev iter's fragment ds_reads done
    #pragma unroll
    for (int j = 0; j < 4; ++j) {
      int oe = j * 2048 + tid * 8;       // linear LDS elem offset (128x64)
      int se = oe ^ (((oe >> 6) & 7) << 3);  // swizzled source elem
      int r = oe >> 6, c = se & 63;
      async16(&A[(size_t)(m0 + r) * K + (k0 + c)], &Alds[j * 2048 + wave * 512]);
      async16(&Bt[(size_t)(n0 + r) * K + (k0 + c)], &Blds[j * 2048 + wave * 512]);
    }
    __syncthreads();                     // drains vmcnt before use
    #pragma unroll
    for (int kk = 0; kk < 2; ++kk) {     // two 32-wide K-slices
      bf16x8 af[4], bfr[4];
      #pragma unroll
      for (int mi = 0; mi < 4; ++mi) {
        int arow = wm * 64 + mi * 16 + ln;
        af[mi] = *(const bf16x8*)&Alds[arow * 64 +
                     ((kk * 32 + qd * 8) ^ ((arow & 7) << 3))];
      }
      #pragma unroll
      for (int ni = 0; ni < 4; ++ni) {
        int brow = wn * 64 + ni * 16 + ln;
        bfr[ni] = *(const bf16x8*)&Blds[brow * 64 +
                     ((kk * 32 + qd * 8) ^ ((brow & 7) << 3))];
      }
      #pragma unroll
      for (int mi = 0; mi < 4; ++mi)
        #pragma unroll
        for (int ni = 0; ni < 4; ++ni)
          acc[mi][ni] = mfma16(af[mi], bfr[ni], acc[mi][ni]);
    }
  }

  // epilogue: C/D layout col=lane&15, row=quad*4+reg  [m89-verified]
  if (MODE == 2) {
    #pragma unroll
    for (int mi = 0; mi < 4; ++mi)
      #pragma unroll
      for (int ni = 0; ni < 4; ++ni)
        #pragma unroll
        for (int r = 0; r < 4; ++r) {
          int row = m0 + wm * 64 + mi * 16 + qd * 4 + r;
          int col = n0 + wn * 64 + ni * 16 + ln;
          outp[(size_t)row * N + col] = acc[mi][ni][r] + bias[col];
        }
  } else {
    const int t  = n0 >> 11;             // 0=q, 1=k, 2=v   (block-uniform)
    const int hh = (n0 & 2047) >> 7;     // head            (block-uniform)
    const int bb = m0 >> 11;             // batch           (block-uniform)
    const int l0 = (m0 & 2047) + wm * 64;
    // Q/K (t<2): interleaved-pair pos = ((ln+ni*16)<<1)|wn; V natural.
    const int d0    = (t != 2) ? (((ln) << 1) | wn) : (wn * 64 + ln);
    const int dstep = (t != 2) ? 32 : 16;
    u16* dst = (t == 0) ? D0 : ((t == 1) ? D1 : D2);
    u16* basep = dst + ((size_t)(bb * H_ + hh) * L_) * HD_;
    #pragma unroll
    for (int mi = 0; mi < 4; ++mi)
      #pragma unroll
      for (int r = 0; r < 4; ++r) {
        int l = l0 + mi * 16 + qd * 4 + r;
        #pragma unroll
        for (int ni = 0; ni < 4; ++ni)
          basep[(size_t)l * HD_ + d0 + ni * dstep] = f2bf(acc[mi][ni][r]);
      }
  }
}

// ---------------------------------------------------------------------------
// Flash attention. grid (16 qtiles, 32 bh), 256 thr (4 waves).
// Q,K,V all (B*H, L, 128) bf16. BM=128, BN=64 keys/iter.
//
// ROUND-12 STRUCTURE, B3 REMOVED (2 barriers/iter instead of 3).
// Dataflow proof that B3 was redundant:
//  - Plds is WAVE-PRIVATE: wave w writes rows [w*32,w*32+32) in softmax and
//    reads exactly those rows in PV. Cross-lane-same-wave LDS communication
//    needs no barrier (DS ops of a wave execute in issue order; compiler
//    inserts the lgkmcnt wait for the read).
//  - Vlds: stores happen before B2, PV reads after; nothing writes Vlds
//    between B2 and PV -> covered by B2.
//  - Klds/Vlds overwrite for iter it+1: QK^T and PV of iter it both
//    complete before any wave passes B1(it+1) -> covered by B1.
//  - B3 had no outstanding vmem to drain (K drained at B2; next V-loads
//    not yet issued) -> pure sync cost, 32x per block, deleted.
//
// Session rules (rounds 4-13):
//  - VGPR <= 128 or occupancy halves (64-granular quantum).
//  - NO sched_barrier/inline-asm fences (pin live ranges, +24 VGPR).
//  - NO defer-max branch (+24 VGPR).
//  - In-block pipelining dead (r4/r8/r13); occupancy hides the latency.
//  - attn is NOT memory-bound (r11: FETCH 139->25 MB cost 11 us).
//
// LDS swizzles (both-sides, rule #21):
//   K/Q tiles: elem = row*128 + (col ^ ((row&7)<<3)); staged via inverse-
//     swizzled GLOBAL source (global_load_lds writes LDS linearly).
//   Vlds [128][64]: elem = row*64 + (col ^ (((row>>1)&7)<<3)).
//   Plds stride-72. LDS = 50 KB -> 3 blocks/CU.
// Deferred l-reduce: lsum kept PER-LANE, quad-reduced once in epilogue.
// ---------------------------------------------------------------------------
__global__ __launch_bounds__(256, 4) void attn_k(
    const u16* __restrict__ Q, const u16* __restrict__ Kb,
    const u16* __restrict__ V, u16* __restrict__ Ao) {
  __shared__ __align__(16) u16 lds[25600];     // 50 KB
  u16* Klds = lds;               // [64 keys][128 d]  (swizzled)
  u16* Vlds = lds + 8192;        // [128 d][64 keys]  (swizzled)
  u16* Plds = lds + 16384;       // [128 q][72], keys 0..63 used
  const int tid = threadIdx.x;
  const int w = tid >> 6, lane = tid & 63;
  const int ln = lane & 15, qd = lane >> 4;
  const int qt = blockIdx.x, bh = blockIdx.y;
  const int b = bh >> 4, h = bh & 15;
  const size_t slab = (size_t)bh * (L_ * HD_);
  const int vd0 = 2 * lane;                    // V staging: d-pair

  // stage Q tile (contiguous 32 KB, overlays K+V) via async16, pre-swizzled
  #pragma unroll
  for (int j = 0; j < 8; ++j) {
    int oe = j * 2048 + w * 512 + lane * 8;        // linear LDS elem offset
    int se = oe ^ (((oe >> 7) & 7) << 3);          // swizzled global source
    async16(&Q[slab + (size_t)qt * 16384 + se], &lds[j * 2048 + w * 512]);
  }
  __syncthreads();
  bf16x8 aq[2][4];                         // Q fragments in registers
  #pragma unroll
  for (int mi = 0; mi < 2; ++mi) {
    int qrow = w * 32 + mi * 16 + ln;
    #pragma unroll
    for (int kc = 0; kc < 4; ++kc)
      aq[mi][kc] = *(const bf16x8*)&lds[qrow * 128 +
                                        ((kc * 32 + qd * 8) ^ ((qrow & 7) << 3))];
  }

  f32x4 o[2][8];
  #pragma unroll
  for (int i = 0; i < 2; ++i)
    #pragma unroll
    for (int j = 0; j < 8; ++j) o[i][j] = (f32x4){0.f, 0.f, 0.f, 0.f};
  float mst[2][4], lsum[2][4];             // lsum = PER-LANE partial sum
  #pragma unroll
  for (int i = 0; i < 2; ++i)
    #pragma unroll
    for (int r = 0; r < 4; ++r) { mst[i][r] = -1e30f; lsum[i][r] = 0.f; }
  const float SC = 0.12751744f;            // (1/sqrt(128)) * log2(e)

  for (int it = 0; it < 32; ++it) {
    // V global loads -> regs (no LDS touch; before barrier for latency)
    unsigned vv[2][8];
    #pragma unroll
    for (int n2 = 0; n2 < 2; ++n2) {
      int key0 = (w + n2 * 4) * 8;
      #pragma unroll
      for (int e = 0; e < 8; ++e)
        vv[n2][e] = *(const unsigned*)&V[slab + (size_t)(it * 64 + key0 + e) * 128 + vd0];
    }
    __syncthreads();                       // B1: prev iter's LDS readers done
    // K tile via async16, source pre-swizzled (see header comment)
    #pragma unroll
    for (int j = 0; j < 4; ++j) {
      int oe = j * 2048 + w * 512 + lane * 8;
      int se = oe ^ (((oe >> 7) & 7) << 3);
      async16(&Kb[slab + (size_t)it * 8192 + se], &Klds[j * 2048 + w * 512]);
    }
    // V transpose stores (swizzled [128][64]; conflict-free, see header)
    {
      int swz = (lane & 7) << 3;           // ((vd0>>1)&7)<<3, vd0 even
      #pragma unroll
      for (int n2 = 0; n2 < 2; ++n2) {
        int key0 = (w + n2 * 4) * 8;
        u16x8 lo, hi;
        #pragma unroll
        for (int e = 0; e < 8; ++e) {
          lo[e] = (u16)(vv[n2][e] & 0xffffu);
          hi[e] = (u16)(vv[n2][e] >> 16);
        }
        *(u16x8*)&Vlds[vd0 * 64 + (key0 ^ swz)] = lo;
        *(u16x8*)&Vlds[(vd0 + 1) * 64 + (key0 ^ swz)] = hi;
      }
    }
    __syncthreads();                       // B2: drains vmcnt (K) + lgkm (V)

    // S = Q K^T  (raw dot products; scale folded into softmax)
    f32x4 sa[2][4];
    #pragma unroll
    for (int i = 0; i < 2; ++i)
      #pragma unroll
      for (int j = 0; j < 4; ++j) sa[i][j] = (f32x4){0.f, 0.f, 0.f, 0.f};
    #pragma unroll
    for (int kc = 0; kc < 4; ++kc) {
      bf16x8 bk[4];
      #pragma unroll
      for (int ni = 0; ni < 4; ++ni) {
        int krow = ni * 16 + ln;
        bk[ni] = *(const bf16x8*)&Klds[krow * 128 +
                                       ((kc * 32 + qd * 8) ^ ((krow & 7) << 3))];
      }
      #pragma unroll
      for (int mi = 0; mi < 2; ++mi)
        #pragma unroll
        for (int ni = 0; ni < 4; ++ni)
          sa[mi][ni] = mfma16(aq[mi][kc], bk[ni], sa[mi][ni]);
    }

    // online softmax per q-row; row r of tile lives on one quad (16 lanes)
    #pragma unroll
    for (int mi = 0; mi < 2; ++mi) {
      #pragma unroll
      for (int r = 0; r < 4; ++r) {
        float tmax = -1e30f;
        #pragma unroll
        for (int ni = 0; ni < 4; ++ni) tmax = fmaxf(tmax, sa[mi][ni][r]);
        tmax *= SC;
        tmax = fmaxf(tmax, __shfl_xor(tmax, 1));
        tmax = fmaxf(tmax, __shfl_xor(tmax, 2));
        tmax = fmaxf(tmax, __shfl_xor(tmax, 4));
        tmax = fmaxf(tmax, __shfl_xor(tmax, 8));
        float mnew = fmaxf(mst[mi][r], tmax);
        float alpha = exp2f(mst[mi][r] - mnew);
        float p[4], rs = 0.f;
        #pragma unroll
        for (int ni = 0; ni < 4; ++ni) {
          p[ni] = exp2f(sa[mi][ni][r] * SC - mnew);
          rs += p[ni];
        }
        lsum[mi][r] = lsum[mi][r] * alpha + rs;  // per-lane partial
        mst[mi][r] = mnew;
        #pragma unroll
        for (int di = 0; di < 8; ++di) o[mi][di][r] *= alpha;
        #pragma unroll
        for (int ni = 0; ni < 4; ++ni)     // P in A-operand layout [q][key]
          Plds[(w * 32 + mi * 16 + qd * 4 + r) * 72 + ni * 16 + ln] = f2bf(p[ni]);
      }
    }

    // NO B3: Plds is wave-private (written and read by the same wave);
    // DS ops of a wave are in-order and the compiler inserts the lgkmcnt
    // wait before the dependent ds_read. Vlds/Klds hazards covered by
    // B2 (this iter) and B1 (next iter).

    // O += P V
    #pragma unroll
    for (int kc = 0; kc < 2; ++kc) {
      bf16x8 ap[2];
      #pragma unroll
      for (int mi = 0; mi < 2; ++mi)
        ap[mi] = *(const bf16x8*)&Plds[(w * 32 + mi * 16 + ln) * 72 + kc * 32 + qd * 8];
      #pragma unroll
      for (int di = 0; di < 8; ++di) {
        int vrow = di * 16 + ln;
        bf16x8 bv = *(const bf16x8*)&Vlds[vrow * 64 +
                         ((kc * 32 + qd * 8) ^ (((vrow >> 1) & 7) << 3))];
        o[0][di] = mfma16(ap[0], bv, o[0][di]);
        o[1][di] = mfma16(ap[1], bv, o[1][di]);
      }
    }
  }

  // epilogue: reduce per-lane lsum across the quad, normalize, write out
  #pragma unroll
  for (int mi = 0; mi < 2; ++mi) {
    #pragma unroll
    for (int r = 0; r < 4; ++r) {
      float l = lsum[mi][r];
      l += __shfl_xor(l, 1);
      l += __shfl_xor(l, 2);
      l += __shfl_xor(l, 4);
      l += __shfl_xor(l, 8);
      float inv = 1.0f / l;
      int lrow = qt * 128 + w * 32 + mi * 16 + qd * 4 + r;
      size_t orow = ((size_t)b * L_ + lrow) * DIM_ + (size_t)h * HD_;
      #pragma unroll
      for (int di = 0; di < 8; ++di)
        Ao[orow + di * 16 + ln] = f2bf(o[mi][di][r] * inv);
    }
  }
}

// ---------------------------------------------------------------------------
extern "C" void kernel_launch(void* const* d_in, const int* in_sizes, int n_in,
                              void* d_out, int out_size, void* d_ws, size_t ws_size,
                              hipStream_t stream) {
  const float* x    = (const float*)d_in[0];
  const float* cs   = (const float*)d_in[1];
  const float* sn   = (const float*)d_in[2];
  const float* wqkv = (const float*)d_in[3];
  const float* wout = (const float*)d_in[4];
  const float* bias = (const float*)d_in[5];
  u16* ws = (u16*)d_ws;

  // Workspace (u16 elems), 92.3 MB total with two time-multiplexed overlaps:
  //   wqkvT 12,582,912  (N=6144 x K=2048 bf16; REUSED for woutT after gemm1)
  //   xbfAo  8,388,608  (x_bf during gemm1; Ao after attn)
  //   Qb/Kbuf/Vbuf 3 x 8,388,608
  u16* wqkvT = ws;
  u16* woutT = ws;                        // same region, written after gemm1
  u16* xbfAo = wqkvT + 12582912;
  u16* Qb    = xbfAo + 8388608;
  u16* Kbuf  = Qb + 8388608;
  u16* Vbuf  = Kbuf + 8388608;

  // 5 launches: cvt+wqkv-transpose merged; wout-transpose+rotary merged
  prepass_k<<<dim3(11264), 256, 0, stream>>>(x, xbfAo, wqkv, wqkvT);
  gemm_bt<1><<<dim3(48, 32), 256, 0, stream>>>(
      xbfAo, wqkvT, Qb, Kbuf, Vbuf, nullptr, nullptr, M_, NQKV_, DIM_);
  post_k<<<dim3(9216), 256, 0, stream>>>(wout, woutT, Qb, Kbuf, cs, sn);
  attn_k<<<dim3(16, 32), 256, 0, stream>>>(Qb, Kbuf, Vbuf, xbfAo);
  gemm_bt<2><<<dim3(16, 32), 256, 0, stream>>>(
      xbfAo, woutT, nullptr, nullptr, nullptr, bias, (float*)d_out, M_, DIM_, DIM_);
}

// Round 16
// 446.412 us; speedup vs baseline: 1.0744x; 1.0059x over previous
//
#include <hip/hip_runtime.h>
#include <cstdint>
#include <cstddef>

typedef unsigned short u16;
typedef __attribute__((ext_vector_type(2))) unsigned short u16x2;
typedef __attribute__((ext_vector_type(4))) unsigned short u16x4;
typedef __attribute__((ext_vector_type(8))) unsigned short u16x8;
typedef __attribute__((ext_vector_type(4))) float f32x4;
typedef __attribute__((ext_vector_type(8))) __bf16 bf16x8;

#define B_    2
#define L_    2048
#define DIM_  2048
#define H_    16
#define HD_   128
#define NQKV_ 6144
#define M_    4096   // B_*L_

__device__ __forceinline__ float b2f(u16 h) {
  union { unsigned u; float f; } v; v.u = ((unsigned)h) << 16; return v.f;
}
__device__ __forceinline__ u16 f2bf(float f) {
  unsigned u = __float_as_uint(f);
  u += 0x7fffu + ((u >> 16) & 1u);   // RNE
  return (u16)(u >> 16);
}
__device__ __forceinline__ f32x4 mfma16(bf16x8 a, bf16x8 b, f32x4 c) {
  return __builtin_amdgcn_mfma_f32_16x16x32_bf16(a, b, c, 0, 0, 0);
}
__device__ __forceinline__ void async16(const void* g, void* l) {
  __builtin_amdgcn_global_load_lds(
      (const __attribute__((address_space(1))) unsigned*)g,
      (__attribute__((address_space(3))) unsigned*)l, 16, 0, 0);
}

// ---------------------------------------------------------------------------
// Vectorized 64x64 transpose+convert tile body (G13):
//  load:  4 iters x f32x4 (16 B/lane);  store: 4 iters x u16x4 (8 B/lane).
//  LDS reads stride 4*66 u16 = 33 dwords -> bank = lane -> conflict-free.
// ---------------------------------------------------------------------------
__device__ __forceinline__ void transpose_tile(
    const float* __restrict__ src, u16* __restrict__ dst,
    u16 (*tile)[66], int tid, int r0, int c0, int R, int C) {
  #pragma unroll
  for (int i = 0; i < 4; ++i) {
    int f = i * 256 + tid;
    int r = f >> 4, c4 = (f & 15) * 4;
    f32x4 v = *(const f32x4*)&src[(size_t)(r0 + r) * C + (c0 + c4)];
    #pragma unroll
    for (int j = 0; j < 4; ++j) tile[r][c4 + j] = f2bf(v[j]);
  }
  __syncthreads();
  #pragma unroll
  for (int i = 0; i < 4; ++i) {
    int f = i * 256 + tid;
    int cr = f >> 4, rp = (f & 15) * 4;
    u16x4 o = {tile[rp][cr], tile[rp + 1][cr], tile[rp + 2][cr], tile[rp + 3][cr]};
    *(u16x4*)&dst[(size_t)(c0 + cr) * R + (r0 + rp)] = o;
  }
}

// ---------------------------------------------------------------------------
// Merged pre-pass: blocks < 4096 do the straight f32->bf16 convert of x
// (8 elems/thread, f32x4 x2 -> u16x8); blocks >= 4096 transpose+convert
// wqkv (2048 x 6144 f32) -> wqkvT (6144 x 2048 bf16). Block-uniform branch.
// ---------------------------------------------------------------------------
__global__ __launch_bounds__(256) void prepass_k(
    const float* __restrict__ x, u16* __restrict__ xbf,
    const float* __restrict__ wqkv, u16* __restrict__ wqkvT) {
  __shared__ u16 tile[64][66];
  const int bid = blockIdx.x;
  if (bid < 4096) {
    int i = (bid * 256 + threadIdx.x) * 8;
    f32x4 a = *(const f32x4*)&x[i];
    f32x4 b = *(const f32x4*)&x[i + 4];
    u16x8 o;
    #pragma unroll
    for (int j = 0; j < 4; ++j) { o[j] = f2bf(a[j]); o[j + 4] = f2bf(b[j]); }
    *(u16x8*)&xbf[i] = o;
  } else {
    const int t = bid - 4096;            // 96 x 32 tile grid (C=6144, R=2048)
    const int by = t / 96, bx = t - by * 96;
    transpose_tile(wqkv, wqkvT, tile, threadIdx.x, by * 64, bx * 64, 2048, 6144);
  }
}

// ---------------------------------------------------------------------------
// Merged post-gemm1 pass: blocks < 1024 transpose+convert wout (2048x2048
// f32) -> woutT (bf16); blocks >= 1024 apply in-place rotary to Q and K
// (INTERLEAVED-PAIR layout: pos 2d = x1(d), 2d+1 = x2(d)); fully vectorized.
// ---------------------------------------------------------------------------
__global__ __launch_bounds__(256) void post_k(
    const float* __restrict__ wout, u16* __restrict__ woutT,
    u16* __restrict__ Q, u16* __restrict__ Kb,
    const float* __restrict__ cs, const float* __restrict__ sn) {
  __shared__ u16 tile[64][66];
  const int bid = blockIdx.x;
  if (bid < 1024) {                      // 32 x 32 tile grid (C=R=2048)
    const int bx = bid & 31, by = bid >> 5;
    transpose_tile(wout, woutT, tile, threadIdx.x, by * 64, bx * 64, 2048, 2048);
  } else {
    const int rb = bid - 1024;           // rotary: 8 rows/block, 2 tensors
    const int tid = threadIdx.x;
    const int tensor = tid >> 7;         // 0 = Q, 1 = K
    const int rsub = (tid >> 4) & 7;
    const int j = tid & 15;
    const int row = rb * 8 + rsub;       // flat (bh*L + l)
    const int l = row & (L_ - 1);
    u16* P = tensor ? Kb : Q;
    size_t base = (size_t)row * HD_ + j * 8;
    u16x8 v = *(const u16x8*)&P[base];
    f32x4 c = *(const f32x4*)&cs[l * 64 + j * 4];
    f32x4 s = *(const f32x4*)&sn[l * 64 + j * 4];
    u16x8 o;
    #pragma unroll
    for (int e = 0; e < 4; ++e) {
      float x1 = b2f(v[2 * e]), x2 = b2f(v[2 * e + 1]);
      o[2 * e]     = f2bf(x1 * c[e] - x2 * s[e]);
      o[2 * e + 1] = f2bf(x2 * c[e] + x1 * s[e]);
    }
    *(u16x8*)&P[base] = o;
  }
}

// ---------------------------------------------------------------------------
// m97-style GEMM, BK=64 (round-12, proven −27 us): C[M,N] = A*Bt^T, bf16,
// async16 staging, 128x128 tile, 256 thr. BK=64 halves barrier count;
// LDS 32 KB. Tiles XOR-swizzled (elem = row*64 + (col ^ ((row&7)<<3)))
// via inverse-swizzled global source (rule #21); post-swizzle bank group
// (kk*4+qd)^(ln&7) = 8 lanes/group = b128 minimum.
// MODE 1: scatter epilogue into Q/K/V; t/h/b hoisted; Q/K interleaved-pair.
// MODE 2: bias-add epilogue, f32 row-major store.
// ---------------------------------------------------------------------------
template <int MODE>
__global__ __launch_bounds__(256) void gemm_bt(
    const u16* __restrict__ A, const u16* __restrict__ Bt,
    u16* __restrict__ D0, u16* __restrict__ D1, u16* __restrict__ D2,
    const float* __restrict__ bias, float* __restrict__ outp,
    int M, int N, int K) {
  __shared__ __align__(16) u16 Alds[128 * 64];
  __shared__ __align__(16) u16 Blds[128 * 64];
  const int tid = threadIdx.x;
  const int wave = tid >> 6;
  const int wm = wave >> 1, wn = wave & 1;
  const int ln = tid & 15, qd = (tid >> 4) & 3;
  const int m0 = blockIdx.y * 128, n0 = blockIdx.x * 128;

  f32x4 acc[4][4];
  #pragma unroll
  for (int i = 0; i < 4; ++i)
    #pragma unroll
    for (int j = 0; j < 4; ++j) acc[i][j] = (f32x4){0.f, 0.f, 0.f, 0.f};

  for (int k0 = 0; k0 < K; k0 += 64) {
    __syncthreads();                     // prev iter's fragment ds_reads done
    #pragma unroll
    for (int j = 0; j < 4; ++j) {
      int oe = j * 2048 + tid * 8;       // linear LDS elem offset (128x64)
      int se = oe ^ (((oe >> 6) & 7) << 3);  // swizzled source elem
      int r = oe >> 6, c = se & 63;
      async16(&A[(size_t)(m0 + r) * K + (k0 + c)], &Alds[j * 2048 + wave * 512]);
      async16(&Bt[(size_t)(n0 + r) * K + (k0 + c)], &Blds[j * 2048 + wave * 512]);
    }
    __syncthreads();                     // drains vmcnt before use
    #pragma unroll
    for (int kk = 0; kk < 2; ++kk) {     // two 32-wide K-slices
      bf16x8 af[4], bfr[4];
      #pragma unroll
      for (int mi = 0; mi < 4; ++mi) {
        int arow = wm * 64 + mi * 16 + ln;
        af[mi] = *(const bf16x8*)&Alds[arow * 64 +
                     ((kk * 32 + qd * 8) ^ ((arow & 7) << 3))];
      }
      #pragma unroll
      for (int ni = 0; ni < 4; ++ni) {
        int brow = wn * 64 + ni * 16 + ln;
        bfr[ni] = *(const bf16x8*)&Blds[brow * 64 +
                     ((kk * 32 + qd * 8) ^ ((brow & 7) << 3))];
      }
      #pragma unroll
      for (int mi = 0; mi < 4; ++mi)
        #pragma unroll
        for (int ni = 0; ni < 4; ++ni)
          acc[mi][ni] = mfma16(af[mi], bfr[ni], acc[mi][ni]);
    }
  }

  // epilogue: C/D layout col=lane&15, row=quad*4+reg  [m89-verified]
  if (MODE == 2) {
    #pragma unroll
    for (int mi = 0; mi < 4; ++mi)
      #pragma unroll
      for (int ni = 0; ni < 4; ++ni)
        #pragma unroll
        for (int r = 0; r < 4; ++r) {
          int row = m0 + wm * 64 + mi * 16 + qd * 4 + r;
          int col = n0 + wn * 64 + ni * 16 + ln;
          outp[(size_t)row * N + col] = acc[mi][ni][r] + bias[col];
        }
  } else {
    const int t  = n0 >> 11;             // 0=q, 1=k, 2=v   (block-uniform)
    const int hh = (n0 & 2047) >> 7;     // head            (block-uniform)
    const int bb = m0 >> 11;             // batch           (block-uniform)
    const int l0 = (m0 & 2047) + wm * 64;
    // Q/K (t<2): interleaved-pair pos = ((ln+ni*16)<<1)|wn; V natural.
    const int d0    = (t != 2) ? (((ln) << 1) | wn) : (wn * 64 + ln);
    const int dstep = (t != 2) ? 32 : 16;
    u16* dst = (t == 0) ? D0 : ((t == 1) ? D1 : D2);
    u16* basep = dst + ((size_t)(bb * H_ + hh) * L_) * HD_;
    #pragma unroll
    for (int mi = 0; mi < 4; ++mi)
      #pragma unroll
      for (int r = 0; r < 4; ++r) {
        int l = l0 + mi * 16 + qd * 4 + r;
        #pragma unroll
        for (int ni = 0; ni < 4; ++ni)
          basep[(size_t)l * HD_ + d0 + ni * dstep] = f2bf(acc[mi][ni][r]);
      }
  }
}

// ---------------------------------------------------------------------------
// Flash attention. grid (16 qtiles, 32 bh), 256 thr (4 waves).
// Q,K,V all (B*H, L, 128) bf16. BM=128, BN=64 keys/iter.
//
// ROUND-15 EXACT (proven: attn 168 us, total 449 us; 116 VGPR, 21% occ).
// 2 barriers/iter (B3 removed; Plds wave-private, Vlds covered by B2,
// Klds/Vlds overwrite covered by B1 of next iter).
//
// Session rules (rounds 4-13):
//  - VGPR <= 128 or occupancy halves (64-granular quantum).
//  - NO sched_barrier/inline-asm fences (pin live ranges, +24 VGPR).
//  - NO defer-max branch (+24 VGPR).
//  - In-block pipelining dead (r4/r8/r13); occupancy hides the latency.
//  - attn is NOT memory-bound (r11: FETCH 139->25 MB cost 11 us).
//
// LDS swizzles (both-sides, rule #21):
//   K/Q tiles: elem = row*128 + (col ^ ((row&7)<<3)); staged via inverse-
//     swizzled GLOBAL source (global_load_lds writes LDS linearly).
//   Vlds [128][64]: elem = row*64 + (col ^ (((row>>1)&7)<<3)).
//   Plds stride-72. LDS = 50 KB -> 3 blocks/CU.
// Deferred l-reduce: lsum kept PER-LANE, quad-reduced once in epilogue.
// ---------------------------------------------------------------------------
__global__ __launch_bounds__(256, 4) void attn_k(
    const u16* __restrict__ Q, const u16* __restrict__ Kb,
    const u16* __restrict__ V, u16* __restrict__ Ao) {
  __shared__ __align__(16) u16 lds[25600];     // 50 KB
  u16* Klds = lds;               // [64 keys][128 d]  (swizzled)
  u16* Vlds = lds + 8192;        // [128 d][64 keys]  (swizzled)
  u16* Plds = lds + 16384;       // [128 q][72], keys 0..63 used
  const int tid = threadIdx.x;
  const int w = tid >> 6, lane = tid & 63;
  const int ln = lane & 15, qd = lane >> 4;
  const int qt = blockIdx.x, bh = blockIdx.y;
  const int b = bh >> 4, h = bh & 15;
  const size_t slab = (size_t)bh * (L_ * HD_);
  const int vd0 = 2 * lane;                    // V staging: d-pair

  // stage Q tile (contiguous 32 KB, overlays K+V) via async16, pre-swizzled
  #pragma unroll
  for (int j = 0; j < 8; ++j) {
    int oe = j * 2048 + w * 512 + lane * 8;        // linear LDS elem offset
    int se = oe ^ (((oe >> 7) & 7) << 3);          // swizzled global source
    async16(&Q[slab + (size_t)qt * 16384 + se], &lds[j * 2048 + w * 512]);
  }
  __syncthreads();
  bf16x8 aq[2][4];                         // Q fragments in registers
  #pragma unroll
  for (int mi = 0; mi < 2; ++mi) {
    int qrow = w * 32 + mi * 16 + ln;
    #pragma unroll
    for (int kc = 0; kc < 4; ++kc)
      aq[mi][kc] = *(const bf16x8*)&lds[qrow * 128 +
                                        ((kc * 32 + qd * 8) ^ ((qrow & 7) << 3))];
  }

  f32x4 o[2][8];
  #pragma unroll
  for (int i = 0; i < 2; ++i)
    #pragma unroll
    for (int j = 0; j < 8; ++j) o[i][j] = (f32x4){0.f, 0.f, 0.f, 0.f};
  float mst[2][4], lsum[2][4];             // lsum = PER-LANE partial sum
  #pragma unroll
  for (int i = 0; i < 2; ++i)
    #pragma unroll
    for (int r = 0; r < 4; ++r) { mst[i][r] = -1e30f; lsum[i][r] = 0.f; }
  const float SC = 0.12751744f;            // (1/sqrt(128)) * log2(e)

  for (int it = 0; it < 32; ++it) {
    // V global loads -> regs (no LDS touch; before barrier for latency)
    unsigned vv[2][8];
    #pragma unroll
    for (int n2 = 0; n2 < 2; ++n2) {
      int key0 = (w + n2 * 4) * 8;
      #pragma unroll
      for (int e = 0; e < 8; ++e)
        vv[n2][e] = *(const unsigned*)&V[slab + (size_t)(it * 64 + key0 + e) * 128 + vd0];
    }
    __syncthreads();                       // B1: prev iter's LDS readers done
    // K tile via async16, source pre-swizzled (see header comment)
    #pragma unroll
    for (int j = 0; j < 4; ++j) {
      int oe = j * 2048 + w * 512 + lane * 8;
      int se = oe ^ (((oe >> 7) & 7) << 3);
      async16(&Kb[slab + (size_t)it * 8192 + se], &Klds[j * 2048 + w * 512]);
    }
    // V transpose stores (swizzled [128][64]; conflict-free, see header)
    {
      int swz = (lane & 7) << 3;           // ((vd0>>1)&7)<<3, vd0 even
      #pragma unroll
      for (int n2 = 0; n2 < 2; ++n2) {
        int key0 = (w + n2 * 4) * 8;
        u16x8 lo, hi;
        #pragma unroll
        for (int e = 0; e < 8; ++e) {
          lo[e] = (u16)(vv[n2][e] & 0xffffu);
          hi[e] = (u16)(vv[n2][e] >> 16);
        }
        *(u16x8*)&Vlds[vd0 * 64 + (key0 ^ swz)] = lo;
        *(u16x8*)&Vlds[(vd0 + 1) * 64 + (key0 ^ swz)] = hi;
      }
    }
    __syncthreads();                       // B2: drains vmcnt (K) + lgkm (V)

    // S = Q K^T  (raw dot products; scale folded into softmax)
    f32x4 sa[2][4];
    #pragma unroll
    for (int i = 0; i < 2; ++i)
      #pragma unroll
      for (int j = 0; j < 4; ++j) sa[i][j] = (f32x4){0.f, 0.f, 0.f, 0.f};
    #pragma unroll
    for (int kc = 0; kc < 4; ++kc) {
      bf16x8 bk[4];
      #pragma unroll
      for (int ni = 0; ni < 4; ++ni) {
        int krow = ni * 16 + ln;
        bk[ni] = *(const bf16x8*)&Klds[krow * 128 +
                                       ((kc * 32 + qd * 8) ^ ((krow & 7) << 3))];
      }
      #pragma unroll
      for (int mi = 0; mi < 2; ++mi)
        #pragma unroll
        for (int ni = 0; ni < 4; ++ni)
          sa[mi][ni] = mfma16(aq[mi][kc], bk[ni], sa[mi][ni]);
    }

    // online softmax per q-row; row r of tile lives on one quad (16 lanes)
    #pragma unroll
    for (int mi = 0; mi < 2; ++mi) {
      #pragma unroll
      for (int r = 0; r < 4; ++r) {
        float tmax = -1e30f;
        #pragma unroll
        for (int ni = 0; ni < 4; ++ni) tmax = fmaxf(tmax, sa[mi][ni][r]);
        tmax *= SC;
        tmax = fmaxf(tmax, __shfl_xor(tmax, 1));
        tmax = fmaxf(tmax, __shfl_xor(tmax, 2));
        tmax = fmaxf(tmax, __shfl_xor(tmax, 4));
        tmax = fmaxf(tmax, __shfl_xor(tmax, 8));
        float mnew = fmaxf(mst[mi][r], tmax);
        float alpha = exp2f(mst[mi][r] - mnew);
        float p[4], rs = 0.f;
        #pragma unroll
        for (int ni = 0; ni < 4; ++ni) {
          p[ni] = exp2f(sa[mi][ni][r] * SC - mnew);
          rs += p[ni];
        }
        lsum[mi][r] = lsum[mi][r] * alpha + rs;  // per-lane partial
        mst[mi][r] = mnew;
        #pragma unroll
        for (int di = 0; di < 8; ++di) o[mi][di][r] *= alpha;
        #pragma unroll
        for (int ni = 0; ni < 4; ++ni)     // P in A-operand layout [q][key]
          Plds[(w * 32 + mi * 16 + qd * 4 + r) * 72 + ni * 16 + ln] = f2bf(p[ni]);
      }
    }

    // NO B3: Plds is wave-private (written and read by the same wave);
    // DS ops of a wave are in-order and the compiler inserts the lgkmcnt
    // wait before the dependent ds_read. Vlds/Klds hazards covered by
    // B2 (this iter) and B1 (next iter).

    // O += P V
    #pragma unroll
    for (int kc = 0; kc < 2; ++kc) {
      bf16x8 ap[2];
      #pragma unroll
      for (int mi = 0; mi < 2; ++mi)
        ap[mi] = *(const bf16x8*)&Plds[(w * 32 + mi * 16 + ln) * 72 + kc * 32 + qd * 8];
      #pragma unroll
      for (int di = 0; di < 8; ++di) {
        int vrow = di * 16 + ln;
        bf16x8 bv = *(const bf16x8*)&Vlds[vrow * 64 +
                         ((kc * 32 + qd * 8) ^ (((vrow >> 1) & 7) << 3))];
        o[0][di] = mfma16(ap[0], bv, o[0][di]);
        o[1][di] = mfma16(ap[1], bv, o[1][di]);
      }
    }
  }

  // epilogue: reduce per-lane lsum across the quad, normalize, write out
  #pragma unroll
  for (int mi = 0; mi < 2; ++mi) {
    #pragma unroll
    for (int r = 0; r < 4; ++r) {
      float l = lsum[mi][r];
      l += __shfl_xor(l, 1);
      l += __shfl_xor(l, 2);
      l += __shfl_xor(l, 4);
      l += __shfl_xor(l, 8);
      float inv = 1.0f / l;
      int lrow = qt * 128 + w * 32 + mi * 16 + qd * 4 + r;
      size_t orow = ((size_t)b * L_ + lrow) * DIM_ + (size_t)h * HD_;
      #pragma unroll
      for (int di = 0; di < 8; ++di)
        Ao[orow + di * 16 + ln] = f2bf(o[mi][di][r] * inv);
    }
  }
}

// ---------------------------------------------------------------------------
extern "C" void kernel_launch(void* const* d_in, const int* in_sizes, int n_in,
                              void* d_out, int out_size, void* d_ws, size_t ws_size,
                              hipStream_t stream) {
  const float* x    = (const float*)d_in[0];
  const float* cs   = (const float*)d_in[1];
  const float* sn   = (const float*)d_in[2];
  const float* wqkv = (const float*)d_in[3];
  const float* wout = (const float*)d_in[4];
  const float* bias = (const float*)d_in[5];
  u16* ws = (u16*)d_ws;

  // Workspace (u16 elems), 92.3 MB total with two time-multiplexed overlaps:
  //   wqkvT 12,582,912  (N=6144 x K=2048 bf16; REUSED for woutT after gemm1)
  //   xbfAo  8,388,608  (x_bf during gemm1; Ao after attn)
  //   Qb/Kbuf/Vbuf 3 x 8,388,608
  u16* wqkvT = ws;
  u16* woutT = ws;                        // same region, written after gemm1
  u16* xbfAo = wqkvT + 12582912;
  u16* Qb    = xbfAo + 8388608;
  u16* Kbuf  = Qb + 8388608;
  u16* Vbuf  = Kbuf + 8388608;

  // 5 launches: cvt+wqkv-transpose merged; wout-transpose+rotary merged
  prepass_k<<<dim3(7168), 256, 0, stream>>>(x, xbfAo, wqkv, wqkvT);
  gemm_bt<1><<<dim3(48, 32), 256, 0, stream>>>(
      xbfAo, wqkvT, Qb, Kbuf, Vbuf, nullptr, nullptr, M_, NQKV_, DIM_);
  post_k<<<dim3(9216), 256, 0, stream>>>(wout, woutT, Qb, Kbuf, cs, sn);
  attn_k<<<dim3(16, 32), 256, 0, stream>>>(Qb, Kbuf, Vbuf, xbfAo);
  gemm_bt<2><<<dim3(16, 32), 256, 0, stream>>>(
      xbfAo, woutT, nullptr, nullptr, nullptr, bias, (float*)d_out, M_, DIM_, DIM_);
}